// Round 1
// baseline (2581.505 us; speedup 1.0000x reference)
//
#include <hip/hip_runtime.h>
#include <hip/hip_bf16.h>
#include <cstdio>
#include <cstddef>

#define T_TOK 2048
#define HID   2048
#define NE    32
#define TOPK  8
#define INTER_ 768
#define LDA 40  // LDS leading dim in shorts for 32-wide K tiles (+8 pad -> 2-way max conflict, free)

typedef __attribute__((ext_vector_type(8))) short bf16x8;
typedef __attribute__((ext_vector_type(4))) float f32x4;

__device__ inline short f2bf(float f) {
    union { float f; unsigned u; } v; v.f = f;
    unsigned r = (v.u + 0x7FFFu + ((v.u >> 16) & 1u)) >> 16;
    return (short)r;
}

// ---------------- router: fp32 logits -> softmax -> top8 -> top-p keep -> renorm ----------------
__global__ __launch_bounds__(256) void router_kernel(
    const float* __restrict__ x, const float* __restrict__ gw,
    __hip_bfloat16* __restrict__ x_bf,
    int* __restrict__ counts, int* __restrict__ tok_list, float* __restrict__ wt_list)
{
    int t = blockIdx.x;
    __shared__ float xs[HID];
    __shared__ float lg[NE];
    const float* xrow = x + (size_t)t * HID;
    for (int i = threadIdx.x; i < HID; i += 256) {
        float v = xrow[i];
        xs[i] = v;
        x_bf[(size_t)t * HID + i] = __float2bfloat16(v);
    }
    __syncthreads();
    int wave = threadIdx.x >> 6, lane = threadIdx.x & 63;
    for (int e8 = 0; e8 < 8; ++e8) {
        int e = wave * 8 + e8;
        const float* wr = gw + (size_t)e * HID;
        float s = 0.f;
        for (int k = lane; k < HID; k += 64) s += xs[k] * wr[k];
        #pragma unroll
        for (int off = 32; off > 0; off >>= 1) s += __shfl_down(s, off);
        if (lane == 0) lg[e] = s;
    }
    __syncthreads();
    if (threadIdx.x == 0) {
        float mx = lg[0];
        for (int e = 1; e < NE; ++e) mx = fmaxf(mx, lg[e]);
        float pr[NE]; float sum = 0.f;
        for (int e = 0; e < NE; ++e) { pr[e] = expf(lg[e] - mx); sum += pr[e]; }
        float inv = 1.f / sum;
        for (int e = 0; e < NE; ++e) pr[e] *= inv;
        // top-8, ties -> lowest index (matches lax.top_k)
        float tv[TOPK]; int ti[TOPK];
        unsigned used = 0u;
        for (int j = 0; j < TOPK; ++j) {
            float bv = -1.f; int be = 0;
            for (int e = 0; e < NE; ++e)
                if (!((used >> e) & 1u) && pr[e] > bv) { bv = pr[e]; be = e; }
            used |= 1u << be;
            tv[j] = bv; ti[j] = be;
        }
        float s8 = 0.f;
        for (int j = 0; j < TOPK; ++j) s8 += tv[j];
        s8 = fmaxf(s8, 1e-12f);
        float c = 0.f; int cnt_lt = 0;
        for (int j = 0; j < TOPK; ++j) { c += tv[j] / s8; if (c < 0.8f) cnt_lt++; }
        int keep = min(cnt_lt + 1, TOPK);
        float sk = 0.f;
        for (int j = 0; j < keep; ++j) sk += tv[j];
        sk = fmaxf(sk, 1e-12f);
        for (int j = 0; j < keep; ++j) {
            float w = tv[j] / sk;
            int e = ti[j];
            int pos = atomicAdd(&counts[e], 1);
            tok_list[e * T_TOK + pos] = t;
            wt_list[e * T_TOK + pos] = w;
        }
    }
}

__global__ void prefix_kernel(const int* __restrict__ counts, int* __restrict__ base) {
    if (threadIdx.x == 0) {
        int s = 0;
        for (int e = 0; e < NE; ++e) { base[e] = s; s += counts[e]; }
        base[NE] = s;
    }
}

// ---------------- GEMM1: h = silu(X Wg^T) * (X Wu^T), gathered rows, bf16 MFMA ----------------
// grid: (32 Mtiles, 12 Ntiles over I=768/64, 32 experts), block 256 (4 waves)
__global__ __launch_bounds__(256) void gemm1_kernel(
    const __hip_bfloat16* __restrict__ x_bf,
    const float* __restrict__ gup,               // [32][1536][2048] fp32
    const int* __restrict__ counts, const int* __restrict__ base,
    const int* __restrict__ tok_list,
    __hip_bfloat16* __restrict__ h_buf)          // [total_pairs][768] bf16
{
    int e = blockIdx.z;
    int cnt = counts[e];
    int m0 = blockIdx.x * 64;
    if (m0 >= cnt) return;
    int n0 = blockIdx.y * 64;

    __shared__ int toks[64];
    __shared__ short As[64 * LDA];
    __shared__ short Bg[64 * LDA];
    __shared__ short Bu[64 * LDA];
    __shared__ float Gt[64 * 68];
    __shared__ float Ut[64 * 68];

    int tid = threadIdx.x;
    if (tid < 64) {
        int r = min(m0 + tid, cnt - 1);
        toks[tid] = tok_list[e * T_TOK + r];
    }
    int wave = tid >> 6, lane = tid & 63;
    int quad = lane >> 4, l16 = lane & 15;

    f32x4 acc[4][2] = {};

    const float* wbase_g = gup + ((size_t)e * 1536 + n0) * HID;
    const float* wbase_u = gup + ((size_t)e * 1536 + 768 + n0) * HID;

    int a_row = tid >> 2, a_k = (tid & 3) * 8;
    int b_sel = tid >> 7;                 // 0: g, 1: u
    int t7 = tid & 127;
    int b_row = t7 >> 1, b_k = (t7 & 1) * 16;
    const float* wb = b_sel ? wbase_u : wbase_g;
    short* Bt = b_sel ? Bu : Bg;

    for (int k0 = 0; k0 < HID; k0 += 32) {
        __syncthreads();
        // stage A (gathered token rows, already bf16)
        uint4 av = *(const uint4*)(x_bf + (size_t)toks[a_row] * HID + k0 + a_k);
        *(uint4*)&As[a_row * LDA + a_k] = av;
        // stage B: 16 fp32 -> 16 bf16
        const float* src = wb + (size_t)b_row * HID + k0 + b_k;
        float4 f0 = *(const float4*)(src);
        float4 f1 = *(const float4*)(src + 4);
        float4 f2 = *(const float4*)(src + 8);
        float4 f3 = *(const float4*)(src + 12);
        short tmp[16];
        tmp[0]=f2bf(f0.x); tmp[1]=f2bf(f0.y); tmp[2]=f2bf(f0.z); tmp[3]=f2bf(f0.w);
        tmp[4]=f2bf(f1.x); tmp[5]=f2bf(f1.y); tmp[6]=f2bf(f1.z); tmp[7]=f2bf(f1.w);
        tmp[8]=f2bf(f2.x); tmp[9]=f2bf(f2.y); tmp[10]=f2bf(f2.z); tmp[11]=f2bf(f2.w);
        tmp[12]=f2bf(f3.x); tmp[13]=f2bf(f3.y); tmp[14]=f2bf(f3.z); tmp[15]=f2bf(f3.w);
        *(uint4*)&Bt[b_row * LDA + b_k]     = *(uint4*)&tmp[0];
        *(uint4*)&Bt[b_row * LDA + b_k + 8] = *(uint4*)&tmp[8];
        __syncthreads();
        // fragments + MFMA
        bf16x8 af[4];
        #pragma unroll
        for (int rt = 0; rt < 4; ++rt)
            af[rt] = *(const bf16x8*)&As[(rt * 16 + l16) * LDA + quad * 8];
        const short* Bsrc = (wave < 2) ? Bg : Bu;
        int c0 = (wave & 1) * 32;
        bf16x8 b0 = *(const bf16x8*)&Bsrc[(c0 + l16) * LDA + quad * 8];
        bf16x8 b1 = *(const bf16x8*)&Bsrc[(c0 + 16 + l16) * LDA + quad * 8];
        #pragma unroll
        for (int rt = 0; rt < 4; ++rt) {
            acc[rt][0] = __builtin_amdgcn_mfma_f32_16x16x32_bf16(af[rt], b0, acc[rt][0], 0, 0, 0);
            acc[rt][1] = __builtin_amdgcn_mfma_f32_16x16x32_bf16(af[rt], b1, acc[rt][1], 0, 0, 0);
        }
    }
    __syncthreads();
    // write g/u tiles to LDS (C/D layout: col = lane&15, row = quad*4+i)
    float* Ot = (wave < 2) ? Gt : Ut;
    int c0 = (wave & 1) * 32;
    #pragma unroll
    for (int rt = 0; rt < 4; ++rt)
        #pragma unroll
        for (int ct = 0; ct < 2; ++ct)
            #pragma unroll
            for (int i = 0; i < 4; ++i) {
                int row = rt * 16 + quad * 4 + i;
                int col = c0 + ct * 16 + l16;
                Ot[row * 68 + col] = acc[rt][ct][i];
            }
    __syncthreads();
    int hb0 = base[e] + m0;
    for (int idx = tid; idx < 64 * 64; idx += 256) {
        int m = idx >> 6, i = idx & 63;
        if (m0 + m < cnt) {
            float g = Gt[m * 68 + i], u = Ut[m * 68 + i];
            float h = (g / (1.f + expf(-g))) * u;
            h_buf[(size_t)(hb0 + m) * INTER_ + n0 + i] = __float2bfloat16(h);
        }
    }
}

// ---------------- GEMM2: out[tok] += w * (h Wd^T), bf16 MFMA + fp32 atomics ----------------
// grid: (32 Mtiles, 16 Ntiles over H=2048/128, 32 experts), block 256
__global__ __launch_bounds__(256) void gemm2_kernel(
    const __hip_bfloat16* __restrict__ h_buf,
    const float* __restrict__ dproj,             // [32][2048][768] fp32
    const int* __restrict__ counts, const int* __restrict__ base,
    const int* __restrict__ tok_list, const float* __restrict__ wt_list,
    float* __restrict__ out)
{
    int e = blockIdx.z;
    int cnt = counts[e];
    int m0 = blockIdx.x * 64;
    if (m0 >= cnt) return;
    int n0 = blockIdx.y * 128;

    __shared__ int toks[64];
    __shared__ float wts[64];
    __shared__ short As[64 * LDA];
    __shared__ short Bs[128 * LDA];

    int tid = threadIdx.x;
    if (tid < 64) {
        int r = min(m0 + tid, cnt - 1);
        toks[tid] = tok_list[e * T_TOK + r];
        wts[tid]  = wt_list[e * T_TOK + r];
    }
    int wave = tid >> 6, lane = tid & 63;
    int quad = lane >> 4, l16 = lane & 15;

    f32x4 acc[4][2] = {};

    const float* wb = dproj + (size_t)e * HID * INTER_ + (size_t)n0 * INTER_;
    int a_row = tid >> 2, a_k = (tid & 3) * 8;
    int b_row = tid >> 1, b_k = (tid & 1) * 16;
    int hb0 = base[e] + m0;
    const __hip_bfloat16* arow = h_buf + (size_t)(base[e] + min(m0 + a_row, cnt - 1)) * INTER_ + a_k;
    const float* brow = wb + (size_t)b_row * INTER_ + b_k;

    for (int k0 = 0; k0 < INTER_; k0 += 32) {
        __syncthreads();
        uint4 av = *(const uint4*)(arow + k0);
        *(uint4*)&As[a_row * LDA + a_k] = av;
        float4 f0 = *(const float4*)(brow + k0);
        float4 f1 = *(const float4*)(brow + k0 + 4);
        float4 f2 = *(const float4*)(brow + k0 + 8);
        float4 f3 = *(const float4*)(brow + k0 + 12);
        short tmp[16];
        tmp[0]=f2bf(f0.x); tmp[1]=f2bf(f0.y); tmp[2]=f2bf(f0.z); tmp[3]=f2bf(f0.w);
        tmp[4]=f2bf(f1.x); tmp[5]=f2bf(f1.y); tmp[6]=f2bf(f1.z); tmp[7]=f2bf(f1.w);
        tmp[8]=f2bf(f2.x); tmp[9]=f2bf(f2.y); tmp[10]=f2bf(f2.z); tmp[11]=f2bf(f2.w);
        tmp[12]=f2bf(f3.x); tmp[13]=f2bf(f3.y); tmp[14]=f2bf(f3.z); tmp[15]=f2bf(f3.w);
        *(uint4*)&Bs[b_row * LDA + b_k]     = *(uint4*)&tmp[0];
        *(uint4*)&Bs[b_row * LDA + b_k + 8] = *(uint4*)&tmp[8];
        __syncthreads();
        bf16x8 af[4];
        #pragma unroll
        for (int rt = 0; rt < 4; ++rt)
            af[rt] = *(const bf16x8*)&As[(rt * 16 + l16) * LDA + quad * 8];
        int cb = wave * 32;
        bf16x8 b0 = *(const bf16x8*)&Bs[(cb + l16) * LDA + quad * 8];
        bf16x8 b1 = *(const bf16x8*)&Bs[(cb + 16 + l16) * LDA + quad * 8];
        #pragma unroll
        for (int rt = 0; rt < 4; ++rt) {
            acc[rt][0] = __builtin_amdgcn_mfma_f32_16x16x32_bf16(af[rt], b0, acc[rt][0], 0, 0, 0);
            acc[rt][1] = __builtin_amdgcn_mfma_f32_16x16x32_bf16(af[rt], b1, acc[rt][1], 0, 0, 0);
        }
    }
    __syncthreads();
    #pragma unroll
    for (int rt = 0; rt < 4; ++rt)
        #pragma unroll
        for (int ct = 0; ct < 2; ++ct)
            #pragma unroll
            for (int i = 0; i < 4; ++i) {
                int row = rt * 16 + quad * 4 + i;
                if (m0 + row < cnt) {
                    int col = n0 + wave * 32 + ct * 16 + l16;
                    float v = acc[rt][ct][i] * wts[row];
                    atomicAdd(&out[(size_t)toks[row] * HID + col], v);
                }
            }
}

extern "C" void kernel_launch(void* const* d_in, const int* in_sizes, int n_in,
                              void* d_out, int out_size, void* d_ws, size_t ws_size,
                              hipStream_t stream)
{
    const float* x   = (const float*)d_in[0];
    const float* gw  = (const float*)d_in[1];
    const float* gup = (const float*)d_in[2];
    const float* dpj = (const float*)d_in[3];
    float* out = (float*)d_out;

    static int printed = 0;
    if (!printed) { fprintf(stderr, "[moe] ws_size=%zu\n", ws_size); printed = 1; }

    char* ws = (char*)d_ws;
    size_t off = 0;
    __hip_bfloat16* x_bf = (__hip_bfloat16*)(ws + off); off += (size_t)T_TOK * HID * 2;
    int* counts = (int*)(ws + off); off += 256;
    int* base   = (int*)(ws + off); off += 256;
    int* tok_list = (int*)(ws + off); off += (size_t)NE * T_TOK * 4;
    float* wt_list = (float*)(ws + off); off += (size_t)NE * T_TOK * 4;
    __hip_bfloat16* h_buf = (__hip_bfloat16*)(ws + off); off += (size_t)T_TOK * TOPK * INTER_ * 2;

    hipMemsetAsync(counts, 0, 256, stream);
    hipMemsetAsync(d_out, 0, (size_t)out_size * sizeof(float), stream);
    router_kernel<<<T_TOK, 256, 0, stream>>>(x, gw, x_bf, counts, tok_list, wt_list);
    prefix_kernel<<<1, 64, 0, stream>>>(counts, base);
    gemm1_kernel<<<dim3(32, 12, 32), 256, 0, stream>>>(x_bf, gup, counts, base, tok_list, h_buf);
    gemm2_kernel<<<dim3(32, 16, 32), 256, 0, stream>>>(h_buf, dpj, counts, base, tok_list, wt_list, out);
}